// Round 1
// baseline (196.917 us; speedup 1.0000x reference)
//
#include <hip/hip_runtime.h>

// SmoothL1 (beta=0.5) masked sum reduction.
// d = outs - labels; ad = |d|
// sl1 = ad < 0.5 ? 0.5*d*d/0.5 : ad - 0.25   (0.5*x/0.5 == x exactly: pow-2)
// mask: ad >= 1.0f/len; out[0] = sum(mask ? sl1 : 0)

#define N_TOTAL 16777216

__device__ __forceinline__ float sl1_term(float o, float l, int len) {
    float d  = o - l;
    float ad = fabsf(d);
    float v  = (ad < 0.5f) ? (d * d) : (ad - 0.25f);
    float boundary = 1.0f / (float)len;   // IEEE divide; matches jnp 1/len
    return (ad >= boundary) ? v : 0.0f;
}

__global__ __launch_bounds__(256) void RegressionLoss_45440753992375_kernel(
        const float* __restrict__ outs,
        const float* __restrict__ labels,
        const int*   __restrict__ lens,
        float* __restrict__ out) {
    const int tid    = blockIdx.x * blockDim.x + threadIdx.x;
    const int stride = gridDim.x * blockDim.x;

    const float4* o4 = (const float4*)outs;
    const float4* l4 = (const float4*)labels;
    const int4*   n4 = (const int4*)lens;
    const int nvec = N_TOTAL / 4;

    float acc = 0.0f;
    for (int i = tid; i < nvec; i += stride) {
        float4 o  = o4[i];
        float4 l  = l4[i];
        int4   ln = n4[i];
        acc += sl1_term(o.x, l.x, ln.x);
        acc += sl1_term(o.y, l.y, ln.y);
        acc += sl1_term(o.z, l.z, ln.z);
        acc += sl1_term(o.w, l.w, ln.w);
    }

    // wave-64 shuffle reduction
    #pragma unroll
    for (int off = 32; off > 0; off >>= 1)
        acc += __shfl_down(acc, off, 64);

    __shared__ float smem[4];  // 256 threads = 4 waves
    const int lane = threadIdx.x & 63;
    const int wid  = threadIdx.x >> 6;
    if (lane == 0) smem[wid] = acc;
    __syncthreads();
    if (threadIdx.x == 0) {
        float bsum = smem[0] + smem[1] + smem[2] + smem[3];
        atomicAdd(out, bsum);   // device-scope by default on CDNA
    }
}

extern "C" void kernel_launch(void* const* d_in, const int* in_sizes, int n_in,
                              void* d_out, int out_size, void* d_ws, size_t ws_size,
                              hipStream_t stream) {
    const float* outs   = (const float*)d_in[0];
    const float* labels = (const float*)d_in[1];
    const int*   lens   = (const int*)d_in[2];
    float* out = (float*)d_out;

    // d_out is poisoned 0xAA before every timed launch — zero it on-stream.
    hipMemsetAsync(out, 0, sizeof(float), stream);

    // 2048 blocks x 256 threads = 8192 waves = 32 waves/CU on 256 CUs.
    RegressionLoss_45440753992375_kernel<<<2048, 256, 0, stream>>>(outs, labels, lens, out);
}